// Round 5
// baseline (411.435 us; speedup 1.0000x reference)
//
#include <hip/hip_runtime.h>

#define NB 8
#define NN 50000
#define NC 64
#define NE 400000

typedef unsigned short us4 __attribute__((ext_vector_type(4)));
typedef unsigned short us8 __attribute__((ext_vector_type(8)));
typedef short s8v __attribute__((ext_vector_type(8)));   // bf16x8 MFMA operand
typedef float f4v __attribute__((ext_vector_type(4)));   // fp32x4 MFMA acc / NT float4

__device__ __forceinline__ float bf2f(unsigned short u) {
  union { unsigned int i; float f; } v; v.i = ((unsigned int)u) << 16; return v.f;
}
__device__ __forceinline__ unsigned short f2bf(float f) {
  union { float f; unsigned int i; } v; v.f = f;
  unsigned int x = v.i;
  return (unsigned short)((x + 0x7FFFu + ((x >> 16) & 1u)) >> 16);  // RNE
}
__device__ __forceinline__ void fma4(float4& a, float s, const float4& v) {
  a.x = fmaf(s, v.x, a.x); a.y = fmaf(s, v.y, a.y);
  a.z = fmaf(s, v.z, a.z); a.w = fmaf(s, v.w, a.w);
}

// ---- gather pipeline primitives --------------------------------------------
// issue8: launch up to 8 record gathers (v-regs only; lap is re-shuffled at
// consume time so a staged group costs 32 VGPR, enabling double-buffering).
__device__ __forceinline__ void issue8(const unsigned short* __restrict__ tb,
                                       int2 myed, int m, int take, us8 (&v)[8]) {
  int rem = take - m; if (rem > 8) rem = 8;
  if (rem == 8) {
#pragma unroll
    for (int u = 0; u < 8; ++u) {
      int c = __shfl(myed.x, m + u, 64);
      v[u] = *(const us8*)&tb[(size_t)c * 512];
    }
  } else {
#pragma unroll
    for (int u = 0; u < 8; ++u)
      if (u < rem) {
        int c = __shfl(myed.x, m + u, 64);
        v[u] = *(const us8*)&tb[(size_t)c * 512];
      }
  }
}
__device__ __forceinline__ void consume8(int2 myed, int m, int take,
                                         const us8 (&v)[8], float (&acc)[8]) {
  int rem = take - m; if (rem > 8) rem = 8;
  if (rem == 8) {
#pragma unroll
    for (int u = 0; u < 8; ++u) {
      float l = __int_as_float(__shfl(myed.y, m + u, 64));
#pragma unroll
      for (int q = 0; q < 8; ++q) acc[q] = fmaf(l, bf2f(v[u][q]), acc[q]);
    }
  } else {
#pragma unroll
    for (int u = 0; u < 8; ++u)
      if (u < rem) {
        float l = __int_as_float(__shfl(myed.y, m + u, 64));
#pragma unroll
        for (int q = 0; q < 8; ++q) acc[q] = fmaf(l, bf2f(v[u][q]), acc[q]);
      }
  }
}

// ---- shared gather-accumulate core (serial groups; fallback paths) ---------
__device__ __forceinline__ void gather_group(
    const unsigned short* __restrict__ tb, const int2* __restrict__ edges,
    int s, int e, int lane, int2 myed, float (&acc)[8]) {
  int jc = s;
  while (jc < e) {
    int take = e - jc; if (take > 64) take = 64;
    if (jc != s) myed = edges[jc + (lane < take ? lane : take - 1)];
    for (int m = 0; m < take; m += 8) {
      us8 v[8];
      issue8(tb, myed, m, take, v);
      consume8(myed, m, take, v, acc);
    }
    jc += take;
  }
}

// ---- pipelined 4-node gather: shared by prop1h and fused's prop2 -----------
// Double-buffered va/vb (compile-time selected): node j+1's first 8 gathers
// are issued before node j's FMA consumption => ~16 gathers in flight.
// emit(j, acc8) stores node j's result.
template <typename EmitFn>
__device__ __forceinline__ void prop4_pipelined(
    const unsigned short* __restrict__ tb, const int2* __restrict__ edges,
    const int* __restrict__ rowptr, const int* __restrict__ cnt,
    int n0, int lane, EmitFn emit) {
  int sj[4], cj[4], tj[4];
#pragma unroll
  for (int j = 0; j < 4; ++j) {
    sj[j] = rowptr[n0 + j]; cj[j] = cnt[n0 + j];
    tj[j] = cj[j] > 64 ? 64 : cj[j];
  }
  int2 med[4];
#pragma unroll
  for (int j = 0; j < 4; ++j) {
    int idx = (tj[j] > 0) ? (sj[j] + (lane < tj[j] ? lane : tj[j] - 1)) : 0;
    med[j] = edges[idx];
  }
  us8 va[8], vb[8];
  if (tj[0] > 0) issue8(tb, med[0], 0, tj[0], va);
#pragma unroll
  for (int j = 0; j < 4; ++j) {
    us8 (&curv)[8] = (j & 1) ? vb : va;
    us8 (&nxtv)[8] = (j & 1) ? va : vb;
    if (j < 3 && tj[j + 1] > 0) issue8(tb, med[j + 1], 0, tj[j + 1], nxtv);
    float acc8[8];
#pragma unroll
    for (int q = 0; q < 8; ++q) acc8[q] = 0.0f;
    if (tj[j] > 0) {
      consume8(med[j], 0, tj[j], curv, acc8);
      // remaining groups of the first window (deg > 8), serial reuse of curv
      for (int m = 8; m < tj[j]; m += 8) {
        issue8(tb, med[j], m, tj[j], curv);
        consume8(med[j], m, tj[j], curv, acc8);
      }
      // >64-edge fallback (essentially never for this graph, kept for correctness)
      if (cj[j] > 64) {
        int rs = sj[j] + 64, re = sj[j] + cj[j];
        int t = re - rs; if (t > 64) t = 64;
        int2 m2 = edges[rs + (lane < t ? lane : t - 1)];
        gather_group(tb, edges, rs, re, lane, m2, acc8);
      }
    }
    emit(j, acc8);
  }
}

// ---- CSR build --------------------------------------------------------------
__global__ void cheb_count(const int* __restrict__ ei, int* __restrict__ cnt) {
  int e = blockIdx.x * blockDim.x + threadIdx.x;
  if (e >= NE) return;
  int r = ei[e], c = ei[NE + e];
  if (r != c) atomicAdd(&cnt[r], 1);
}

// wave-aggregated allocation: ONE atomic per wave instead of one per thread
// (50000 same-address device-scope atomics serialized across 8 XCDs was the
// suspected hidden serial cost in the old version).
__global__ void cheb_offsets(const int* __restrict__ cnt, float* __restrict__ dinv,
                             int* __restrict__ rowptr, int* __restrict__ cur,
                             int* __restrict__ total) {
  int n = blockIdx.x * blockDim.x + threadIdx.x;
  int lane = threadIdx.x & 63;
  bool valid = n < NN;
  int c = valid ? cnt[n] : 0;
  // wave-inclusive scan
  int inc = c;
#pragma unroll
  for (int d = 1; d < 64; d <<= 1) {
    int t = __shfl_up(inc, d, 64);
    if (lane >= d) inc += t;
  }
  int wtot = __shfl(inc, 63, 64);
  int base = 0;
  if (lane == 63) base = atomicAdd(total, wtot);
  base = __shfl(base, 63, 64);
  int s = base + inc - c;   // exclusive position (bucket order irrelevant)
  if (valid) {
    dinv[n] = (c > 0) ? rsqrtf((float)c) : 0.0f;
    rowptr[n] = s;
    cur[n] = s;
  }
}

__global__ void cheb_scatter(const int* __restrict__ ei, const float* __restrict__ dinv,
                             int* __restrict__ cur, int2* __restrict__ edges) {
  int e = blockIdx.x * blockDim.x + threadIdx.x;
  if (e >= NE) return;
  int r = ei[e], c = ei[NE + e];
  if (r == c) return;
  int pos = atomicAdd(&cur[r], 1);
  float lap = -dinv[r] * dinv[c];
  edges[pos] = make_int2(c, __float_as_int(lap));
}

// ---- Wc fp32 (fallback path only) ------------------------------------------
__global__ void cheb_wc(const float* __restrict__ w, float* __restrict__ wc) {
  int i = blockIdx.x * blockDim.x + threadIdx.x;
  if (i >= NC * NC) return;
  float w0 = w[i];
  float w1 = w[NC * NC + i];
  float w2 = w[2 * NC * NC + i];
  wc[i] = w0 - w2;
  wc[NC * NC + i] = w1;
  wc[2 * NC * NC + i] = 2.0f * w2;
}

// ---- pack Wc into bf16 B-fragment order ------------------------------------
// pack[(((ks*4+nt)*64)+l)*8+jj] = Wc[ks*32+(l>>4)*8+jj][nt*16+(l&15)]
__global__ void cheb_wpack(const float* __restrict__ w, unsigned short* __restrict__ pack) {
  int t = blockIdx.x * blockDim.x + threadIdx.x;
  if (t >= 6 * 4 * 64 * 8) return;
  int jj = t & 7;
  int l  = (t >> 3) & 63;
  int nt = (t >> 9) & 3;
  int ks = t >> 11;
  int k = ks * 32 + ((l >> 4) * 8) + jj;     // 0..191
  int o = nt * 16 + (l & 15);                // 0..63
  int ki = k & 63, ch = k >> 6;
  float v;
  if (ch == 0)      v = w[ki * 64 + o] - w[2 * 4096 + ki * 64 + o];
  else if (ch == 1) v = w[4096 + ki * 64 + o];
  else              v = 2.0f * w[2 * 4096 + ki * 64 + o];
  pack[t] = f2bf(v);
}

// ---- convert x (bnc fp32) -> xh (nbc bf16; node record = 1KB contiguous) ---
__global__ __launch_bounds__(256) void cheb_convert(
    const float* __restrict__ x, unsigned short* __restrict__ xh) {
  int t = blockIdx.x * blockDim.x + threadIdx.x;
  if (t >= NN * 128) return;
  int n = t >> 7;
  int rem = t & 127;
  int b = rem >> 4;
  int c4 = (rem & 15) * 4;
  f4v v = __builtin_nontemporal_load((const f4v*)&x[((size_t)b * NN + n) * 64 + c4]);
  us4 o;
  o[0] = f2bf(v[0]); o[1] = f2bf(v[1]); o[2] = f2bf(v[2]); o[3] = f2bf(v[3]);
  *(us4*)&xh[(size_t)n * 512 + b * 64 + c4] = o;
}

// ---- prop1h: tx1h[n] = sum lap * xh[col]; 4 nodes per wave, pipelined ------
// Same double-buffered cross-node pipeline as cheb_fused's prop2 phase.
// NN = 50000 = 3125 blocks x 4 waves x 4 nodes exactly.
__global__ __launch_bounds__(256) void cheb_prop1h(
    const unsigned short* __restrict__ tin, unsigned short* __restrict__ tout,
    const int* __restrict__ rowptr, const int* __restrict__ cnt,
    const int2* __restrict__ edges) {
  int wv = (blockIdx.x << 2) + (threadIdx.x >> 6);
  int n0 = wv * 4;
  if (n0 >= NN) return;
  int lane = threadIdx.x & 63;
  const unsigned short* tb = tin + lane * 8;
  prop4_pipelined(tb, edges, rowptr, cnt, n0, lane,
                  [&](int j, float (&acc8)[8]) {
    us8 o;
#pragma unroll
    for (int q = 0; q < 8; ++q) o[q] = f2bf(acc8[q]);
    *(us8*)&tout[(size_t)(n0 + j) * 512 + lane * 8] = o;
  });
}

// ---- fused prop2 + MFMA GEMM -----------------------------------------------
// Each wave owns 32 rows (4 nodes x 8 batches, rn = n*8+b).
// prop2 uses the pipelined 4-node gather into wave-private LDS tile P;
// MFMA: 6 ksteps x (2 M x 4 N) 16x16x32_bf16; A-frags for ks 0..3 stream
// straight from xh/tx1h global (single-use -> nontemporal), ks 4..5 from P.
__global__ __launch_bounds__(256) void cheb_fused(
    const unsigned short* __restrict__ xh, const unsigned short* __restrict__ tx1h,
    const int* __restrict__ rowptr, const int* __restrict__ cnt,
    const int2* __restrict__ edges, const unsigned short* __restrict__ pack,
    const float* __restrict__ bias, float* __restrict__ out) {
  __shared__ unsigned short Pb[4][32][72];   // stride 72 shorts = 144B, 16B-aligned rows
  int w = threadIdx.x >> 6, lane = threadIdx.x & 63;
  int row0 = blockIdx.x * 128 + w * 32;
  int n0 = row0 >> 3;
  unsigned short (*P)[72] = Pb[w];

  // prop2 for the wave's 4 nodes -> P  (lane = (b:3)(ch8:3))
  const unsigned short* tb = tx1h + lane * 8;
  prop4_pipelined(tb, edges, rowptr, cnt, n0, lane,
                  [&](int j, float (&acc8)[8]) {
    us8 o;
#pragma unroll
    for (int q = 0; q < 8; ++q) o[q] = f2bf(acc8[q]);
    *(us8*)&P[j * 8 + (lane >> 3)][(lane & 7) * 8] = o;
  });

  // MFMA: 2 M-tiles x 4 N-tiles, K=192 in 6 steps of 32
  f4v acc[2][4];
#pragma unroll
  for (int mt = 0; mt < 2; ++mt)
#pragma unroll
    for (int nt = 0; nt < 4; ++nt) acc[mt][nt] = (f4v){0.f, 0.f, 0.f, 0.f};

  int am = lane & 15, aq = (lane >> 4) * 8;
#pragma unroll
  for (int ks = 0; ks < 6; ++ks) {
    s8v a0, a1;
    if (ks < 2) {
      a0 = __builtin_nontemporal_load((const s8v*)&xh[(size_t)(row0 + am) * 64 + ks * 32 + aq]);
      a1 = __builtin_nontemporal_load((const s8v*)&xh[(size_t)(row0 + 16 + am) * 64 + ks * 32 + aq]);
    } else if (ks < 4) {
      a0 = __builtin_nontemporal_load((const s8v*)&tx1h[(size_t)(row0 + am) * 64 + (ks - 2) * 32 + aq]);
      a1 = __builtin_nontemporal_load((const s8v*)&tx1h[(size_t)(row0 + 16 + am) * 64 + (ks - 2) * 32 + aq]);
    } else {
      a0 = *(const s8v*)&P[am][(ks - 4) * 32 + aq];
      a1 = *(const s8v*)&P[16 + am][(ks - 4) * 32 + aq];
    }
#pragma unroll
    for (int nt = 0; nt < 4; ++nt) {
      s8v b = *(const s8v*)&pack[(((size_t)(ks * 4 + nt) * 64) + lane) * 8];
      acc[0][nt] = __builtin_amdgcn_mfma_f32_16x16x32_bf16(a0, b, acc[0][nt], 0, 0, 0);
      acc[1][nt] = __builtin_amdgcn_mfma_f32_16x16x32_bf16(a1, b, acc[1][nt], 0, 0, 0);
    }
  }

  // epilogue: + bias, NT store to out (bnc fp32). C/D: row=(lane>>4)*4+r, col=lane&15
  float bv[4];
#pragma unroll
  for (int nt = 0; nt < 4; ++nt) bv[nt] = bias[nt * 16 + (lane & 15)];
#pragma unroll
  for (int mt = 0; mt < 2; ++mt)
#pragma unroll
    for (int r = 0; r < 4; ++r) {
      int rl = mt * 16 + (lane >> 4) * 4 + r;
      int rn = row0 + rl;
      int b = rn & 7, nn = rn >> 3;
      float* orow = &out[((size_t)b * NN + nn) * 64 + (lane & 15)];
#pragma unroll
      for (int nt = 0; nt < 4; ++nt)
        __builtin_nontemporal_store(acc[mt][nt][r] + bv[nt], &orow[nt * 16]);
    }
}

// ---- fallback fp32 kernels (small-ws tiers) --------------------------------
__global__ __launch_bounds__(256) void cheb_prop(
    const float* __restrict__ tin, float* __restrict__ tout,
    const int* __restrict__ rowptr, const int* __restrict__ cnt,
    const int2* __restrict__ edges, int nwaves) {
  int wid = (blockIdx.x << 2) + (threadIdx.x >> 6);
  if (wid >= nwaves) return;
  int lane = threadIdx.x & 63;
  int b = wid / NN;
  int n = wid - b * NN;
  int s = rowptr[n];
  int e = s + cnt[n];
  const float* base = tin + (size_t)b * NN * NC;
  float acc = 0.0f;
  for (int j = s; j < e; ++j) {
    int2 ed = edges[j];
    acc += __int_as_float(ed.y) * base[(size_t)ed.x * NC + lane];
  }
  tout[((size_t)b * NN + n) * NC + lane] = acc;
}

__global__ __launch_bounds__(256) void cheb_gemm2(
    const float* __restrict__ x, const float* __restrict__ tx1,
    const float* ptx1, const float* __restrict__ wc,
    const float* __restrict__ bias, float* out, int nrows) {
  __shared__ float At[128][64];
  __shared__ float Ws[64][64];
  int tid = threadIdx.x;
  int tx = tid & 15;
  int ty = tid >> 4;
  long row0 = (long)blockIdx.x * 128;
  int sk4 = (tid & 15) * 4;
  int srb = tid >> 4;
  const float* sp[3] = {x, tx1, ptx1};
  float4 pa[8], pw[4];
  auto fetch = [&](int ch) {
    const float* s0 = sp[ch];
#pragma unroll
    for (int rr = 0; rr < 8; ++rr) {
      int roff = srb + rr * 16;
      if (row0 + roff < nrows)
        pa[rr] = *(const float4*)&s0[(size_t)(row0 + roff) * NC + sk4];
      else
        pa[rr] = make_float4(0.f, 0.f, 0.f, 0.f);
    }
#pragma unroll
    for (int ww = 0; ww < 4; ++ww) {
      int e4 = tid + 256 * ww;
      pw[ww] = *(const float4*)&wc[ch * 4096 + (e4 >> 4) * 64 + (e4 & 15) * 4];
    }
  };
  auto commit = [&]() {
#pragma unroll
    for (int rr = 0; rr < 8; ++rr)
      *(float4*)&At[srb + rr * 16][sk4] = pa[rr];
#pragma unroll
    for (int ww = 0; ww < 4; ++ww) {
      int e4 = tid + 256 * ww;
      *(float4*)&Ws[e4 >> 4][(e4 & 15) * 4] = pw[ww];
    }
  };
  float4 acc[8];
#pragma unroll
  for (int i = 0; i < 8; ++i) acc[i] = make_float4(0.f, 0.f, 0.f, 0.f);
  fetch(0);
  commit();
  for (int ch = 0; ch < 3; ++ch) {
    __syncthreads();
    if (ch < 2) fetch(ch + 1);
#pragma unroll 4
    for (int k4 = 0; k4 < 16; ++k4) {
      float4 w0 = *(float4*)&Ws[k4 * 4 + 0][tx * 4];
      float4 w1 = *(float4*)&Ws[k4 * 4 + 1][tx * 4];
      float4 w2 = *(float4*)&Ws[k4 * 4 + 2][tx * 4];
      float4 w3 = *(float4*)&Ws[k4 * 4 + 3][tx * 4];
#pragma unroll
      for (int i = 0; i < 8; ++i) {
        float4 a = *(float4*)&At[ty * 8 + i][k4 * 4];
        fma4(acc[i], a.x, w0);
        fma4(acc[i], a.y, w1);
        fma4(acc[i], a.z, w2);
        fma4(acc[i], a.w, w3);
      }
    }
    __syncthreads();
    if (ch < 2) commit();
  }
  float4 bb4 = *(const float4*)&bias[tx * 4];
#pragma unroll
  for (int i = 0; i < 8; ++i) {
    long r = row0 + ty * 8 + i;
    if (r >= nrows) continue;
    float4 o = make_float4(acc[i].x + bb4.x, acc[i].y + bb4.y,
                           acc[i].z + bb4.z, acc[i].w + bb4.w);
    *(float4*)&out[(size_t)r * NC + tx * 4] = o;
  }
}

extern "C" void kernel_launch(void* const* d_in, const int* in_sizes, int n_in,
                              void* d_out, int out_size, void* d_ws, size_t ws_size,
                              hipStream_t stream) {
  (void)in_sizes; (void)n_in; (void)out_size;
  const float* x    = (const float*)d_in[0];
  const float* w    = (const float*)d_in[1];
  const float* bias = (const float*)d_in[2];
  const int*   ei   = (const int*)d_in[3];
  float* out = (float*)d_out;
  char* ws = (char*)d_ws;

  size_t off = 0;
  auto alloc = [&](size_t bytes) -> void* {
    void* p = (void*)(ws + off);
    off = (off + bytes + 255) & ~(size_t)255;
    return p;
  };
  int* cnt      = (int*)alloc((size_t)(NN + 1) * sizeof(int));
  int* total    = cnt + NN;
  int* rowptr   = (int*)alloc((size_t)NN * sizeof(int));
  int* cur      = (int*)alloc((size_t)NN * sizeof(int));
  float* dinv   = (float*)alloc((size_t)NN * sizeof(float));
  int2* edges   = (int2*)alloc((size_t)NE * sizeof(int2));
  float* wcb    = (float*)alloc((size_t)3 * NC * NC * sizeof(float));
  unsigned short* pack = (unsigned short*)alloc((size_t)6 * 4 * 64 * 8 * sizeof(unsigned short));
  size_t small_end = off;

  hipMemsetAsync(cnt, 0, (NN + 1) * sizeof(int), stream);
  cheb_count  <<<(NE + 255) / 256, 256, 0, stream>>>(ei, cnt);
  cheb_offsets<<<(NN + 255) / 256, 256, 0, stream>>>(cnt, dinv, rowptr, cur, total);
  cheb_scatter<<<(NE + 255) / 256, 256, 0, stream>>>(ei, dinv, cur, edges);

  const size_t fieldHB = (size_t)NN * 512 * sizeof(unsigned short);  // 51.2 MB
  const size_t perbB   = (size_t)NN * NC * sizeof(float);            // 12.8 MB

  if (ws_size >= small_end + 2 * fieldHB + 256) {
    // Tier A: bf16 pipeline with fused prop2+MFMA GEMM
    unsigned short* xh   = (unsigned short*)alloc(fieldHB);
    unsigned short* tx1h = (unsigned short*)alloc(fieldHB);
    cheb_wpack  <<<(6 * 4 * 64 * 8 + 255) / 256, 256, 0, stream>>>(w, pack);
    cheb_convert<<<(NN * 128) / 256, 256, 0, stream>>>(x, xh);
    cheb_prop1h <<<NN / 16, 256, 0, stream>>>(xh, tx1h, rowptr, cnt, edges);
    cheb_fused  <<<(NB * NN) / 128, 256, 0, stream>>>(
        xh, tx1h, rowptr, cnt, edges, pack, bias, out);
  } else if (ws_size >= small_end + 2 * perbB + 256) {
    // Tier B: per-batch fp32 fallback
    cheb_wc<<<(NC * NC + 255) / 256, 256, 0, stream>>>(w, wcb);
    float* tx1b  = (float*)alloc(perbB);
    float* ptx1b = (float*)alloc(perbB);
    for (int b = 0; b < NB; ++b) {
      const float* xb = x + (size_t)b * NN * NC;
      float* outb = out + (size_t)b * NN * NC;
      cheb_prop<<<(NN + 3) / 4, 256, 0, stream>>>(xb, tx1b, rowptr, cnt, edges, NN);
      cheb_prop<<<(NN + 3) / 4, 256, 0, stream>>>(tx1b, ptx1b, rowptr, cnt, edges, NN);
      cheb_gemm2<<<(NN + 127) / 128, 256, 0, stream>>>(
          xb, tx1b, ptx1b, wcb, bias, outb, NN);
    }
  } else {
    // Tier C: per-batch fp32, ptx1 via out slice (gemm stages before writes)
    cheb_wc<<<(NC * NC + 255) / 256, 256, 0, stream>>>(w, wcb);
    float* tx1b = (float*)alloc(perbB);
    for (int b = 0; b < NB; ++b) {
      const float* xb = x + (size_t)b * NN * NC;
      float* outb = out + (size_t)b * NN * NC;
      cheb_prop<<<(NN + 3) / 4, 256, 0, stream>>>(xb, tx1b, rowptr, cnt, edges, NN);
      cheb_prop<<<(NN + 3) / 4, 256, 0, stream>>>(tx1b, outb, rowptr, cnt, edges, NN);
      cheb_gemm2<<<(NN + 127) / 128, 256, 0, stream>>>(
          xb, tx1b, outb, wcb, bias, outb, NN);
    }
  }
}

// Round 6
// 369.945 us; speedup vs baseline: 1.1122x; 1.1122x over previous
//
#include <hip/hip_runtime.h>

#define NB 8
#define NN 50000
#define NC 64
#define NE 400000

typedef unsigned short us4 __attribute__((ext_vector_type(4)));
typedef unsigned short us8 __attribute__((ext_vector_type(8)));
typedef short s8v __attribute__((ext_vector_type(8)));   // bf16x8 MFMA operand
typedef float f4v __attribute__((ext_vector_type(4)));   // fp32x4 MFMA acc / NT float4

__device__ __forceinline__ float bf2f(unsigned short u) {
  union { unsigned int i; float f; } v; v.i = ((unsigned int)u) << 16; return v.f;
}
__device__ __forceinline__ unsigned short f2bf(float f) {
  union { float f; unsigned int i; } v; v.f = f;
  unsigned int x = v.i;
  return (unsigned short)((x + 0x7FFFu + ((x >> 16) & 1u)) >> 16);  // RNE
}
__device__ __forceinline__ void fma4(float4& a, float s, const float4& v) {
  a.x = fmaf(s, v.x, a.x); a.y = fmaf(s, v.y, a.y);
  a.z = fmaf(s, v.z, a.z); a.w = fmaf(s, v.w, a.w);
}

// ---- shared gather-accumulate core (R0 form: serial 8-groups, tail-elided) --
// BW-bound regime (measured: dur == hbm_bytes / 3.78 TB/s for both R0 and the
// deeper-pipelined R5 variant) -> keep the low-VGPR serial structure; deeper
// in-wave pipelining only added spill traffic (+81 MB, +20 us).
__device__ __forceinline__ void gather_group(
    const unsigned short* __restrict__ tb, const int2* __restrict__ edges,
    int s, int e, int lane, int2 myed, float (&acc)[8]) {
  int jc = s;
  while (jc < e) {
    int take = e - jc; if (take > 64) take = 64;
    if (jc != s) myed = edges[jc + (lane < take ? lane : take - 1)];
    int full = take & ~7;
    int m = 0;
    for (; m < full; m += 8) {
      us8 v[8]; float lp[8];
#pragma unroll
      for (int u = 0; u < 8; ++u) {
        int c = __shfl(myed.x, m + u, 64);
        lp[u] = __int_as_float(__shfl(myed.y, m + u, 64));
        v[u] = *(const us8*)&tb[(size_t)c * 512];
      }
#pragma unroll
      for (int u = 0; u < 8; ++u)
#pragma unroll
        for (int q = 0; q < 8; ++q) acc[q] = fmaf(lp[u], bf2f(v[u][q]), acc[q]);
    }
    if (m < take) {                      // wave-uniform tail, rem in [1,7]
      int rem = take - m;
      us8 v[8]; float lp[8];
#pragma unroll
      for (int u = 0; u < 8; ++u) {
        if (u < rem) {
          int c = __shfl(myed.x, m + u, 64);
          lp[u] = __int_as_float(__shfl(myed.y, m + u, 64));
          v[u] = *(const us8*)&tb[(size_t)c * 512];
        }
      }
#pragma unroll
      for (int u = 0; u < 8; ++u) {
        if (u < rem) {
#pragma unroll
          for (int q = 0; q < 8; ++q) acc[q] = fmaf(lp[u], bf2f(v[u][q]), acc[q]);
        }
      }
    }
    jc += take;
  }
}

// ---- CSR build --------------------------------------------------------------
__global__ void cheb_count(const int* __restrict__ ei, int* __restrict__ cnt) {
  int e = blockIdx.x * blockDim.x + threadIdx.x;
  if (e >= NE) return;
  int r = ei[e], c = ei[NE + e];
  if (r != c) atomicAdd(&cnt[r], 1);
}

// wave-aggregated allocation: ONE atomic per wave instead of one per thread
__global__ void cheb_offsets(const int* __restrict__ cnt, float* __restrict__ dinv,
                             int* __restrict__ rowptr, int* __restrict__ cur,
                             int* __restrict__ total) {
  int n = blockIdx.x * blockDim.x + threadIdx.x;
  int lane = threadIdx.x & 63;
  bool valid = n < NN;
  int c = valid ? cnt[n] : 0;
  int inc = c;
#pragma unroll
  for (int d = 1; d < 64; d <<= 1) {
    int t = __shfl_up(inc, d, 64);
    if (lane >= d) inc += t;
  }
  int wtot = __shfl(inc, 63, 64);
  int base = 0;
  if (lane == 63) base = atomicAdd(total, wtot);
  base = __shfl(base, 63, 64);
  int s = base + inc - c;   // exclusive position (bucket order irrelevant)
  if (valid) {
    dinv[n] = (c > 0) ? rsqrtf((float)c) : 0.0f;
    rowptr[n] = s;
    cur[n] = s;
  }
}

__global__ void cheb_scatter(const int* __restrict__ ei, const float* __restrict__ dinv,
                             int* __restrict__ cur, int2* __restrict__ edges) {
  int e = blockIdx.x * blockDim.x + threadIdx.x;
  if (e >= NE) return;
  int r = ei[e], c = ei[NE + e];
  if (r == c) return;
  int pos = atomicAdd(&cur[r], 1);
  float lap = -dinv[r] * dinv[c];
  edges[pos] = make_int2(c, __float_as_int(lap));
}

// ---- Wc fp32 (fallback path only) ------------------------------------------
__global__ void cheb_wc(const float* __restrict__ w, float* __restrict__ wc) {
  int i = blockIdx.x * blockDim.x + threadIdx.x;
  if (i >= NC * NC) return;
  float w0 = w[i];
  float w1 = w[NC * NC + i];
  float w2 = w[2 * NC * NC + i];
  wc[i] = w0 - w2;
  wc[NC * NC + i] = w1;
  wc[2 * NC * NC + i] = 2.0f * w2;
}

// ---- pack Wc into bf16 B-fragment order ------------------------------------
// pack[(((ks*4+nt)*64)+l)*8+jj] = Wc[ks*32+(l>>4)*8+jj][nt*16+(l&15)]
__global__ void cheb_wpack(const float* __restrict__ w, unsigned short* __restrict__ pack) {
  int t = blockIdx.x * blockDim.x + threadIdx.x;
  if (t >= 6 * 4 * 64 * 8) return;
  int jj = t & 7;
  int l  = (t >> 3) & 63;
  int nt = (t >> 9) & 3;
  int ks = t >> 11;
  int k = ks * 32 + ((l >> 4) * 8) + jj;     // 0..191
  int o = nt * 16 + (l & 15);                // 0..63
  int ki = k & 63, ch = k >> 6;
  float v;
  if (ch == 0)      v = w[ki * 64 + o] - w[2 * 4096 + ki * 64 + o];
  else if (ch == 1) v = w[4096 + ki * 64 + o];
  else              v = 2.0f * w[2 * 4096 + ki * 64 + o];
  pack[t] = f2bf(v);
}

// ---- convert x (bnc fp32) -> xh (nbc bf16; node record = 1KB contiguous) ---
__global__ __launch_bounds__(256) void cheb_convert(
    const float* __restrict__ x, unsigned short* __restrict__ xh) {
  int t = blockIdx.x * blockDim.x + threadIdx.x;
  if (t >= NN * 128) return;
  int n = t >> 7;
  int rem = t & 127;
  int b = rem >> 4;
  int c4 = (rem & 15) * 4;
  f4v v = __builtin_nontemporal_load((const f4v*)&x[((size_t)b * NN + n) * 64 + c4]);
  us4 o;
  o[0] = f2bf(v[0]); o[1] = f2bf(v[1]); o[2] = f2bf(v[2]); o[3] = f2bf(v[3]);
  *(us4*)&xh[(size_t)n * 512 + b * 64 + c4] = o;
}

// ---- prop1h: tx1h[n] = sum lap * xh[col]; one wave per node (R0 form) ------
__global__ __launch_bounds__(256) void cheb_prop1h(
    const unsigned short* __restrict__ tin, unsigned short* __restrict__ tout,
    const int* __restrict__ rowptr, const int* __restrict__ cnt,
    const int2* __restrict__ edges) {
  int n = (blockIdx.x << 2) + (threadIdx.x >> 6);
  if (n >= NN) return;
  int lane = threadIdx.x & 63;
  int s = rowptr[n], c = cnt[n];
  const unsigned short* tb = tin + lane * 8;
  float acc[8];
#pragma unroll
  for (int q = 0; q < 8; ++q) acc[q] = 0.0f;
  if (c > 0) {
    int t0 = c > 64 ? 64 : c;
    int2 myed = edges[s + (lane < t0 ? lane : t0 - 1)];
    gather_group(tb, edges, s, s + c, lane, myed, acc);
  }
  us8 o;
#pragma unroll
  for (int q = 0; q < 8; ++q) o[q] = f2bf(acc[q]);
  *(us8*)&tout[(size_t)n * 512 + lane * 8] = o;
}

// ---- fused prop2 + MFMA GEMM (R0 form + NT-policy fix) ----------------------
// NT-policy change this round: ks2-3 A-frag loads of tx1h are REGULAR loads
// (was nontemporal). tx1h is simultaneously the gather-hot working set of this
// kernel; NT-marking those lines invites early L2/L3 eviction -> the ~80 MB of
// gather re-fetch seen in FETCH_SIZE (237 MB vs ~157 MB unique). xh streams and
// out stores stay NT (never re-read).
__global__ __launch_bounds__(256) void cheb_fused(
    const unsigned short* __restrict__ xh, const unsigned short* __restrict__ tx1h,
    const int* __restrict__ rowptr, const int* __restrict__ cnt,
    const int2* __restrict__ edges, const unsigned short* __restrict__ pack,
    const float* __restrict__ bias, float* __restrict__ out) {
  __shared__ unsigned short Pb[4][32][72];   // stride 72 shorts = 144B, 16B-aligned rows
  int w = threadIdx.x >> 6, lane = threadIdx.x & 63;
  int row0 = blockIdx.x * 128 + w * 32;
  int n0 = row0 >> 3;
  unsigned short (*P)[72] = Pb[w];

  // hoisted CSR metadata + first-window edge vectors for all 4 nodes
  int sj[4], cj[4];
#pragma unroll
  for (int j = 0; j < 4; ++j) { sj[j] = rowptr[n0 + j]; cj[j] = cnt[n0 + j]; }
  int2 med[4];
#pragma unroll
  for (int j = 0; j < 4; ++j) {
    int t0 = cj[j] > 64 ? 64 : cj[j];
    int idx = (t0 > 0) ? (sj[j] + (lane < t0 ? lane : t0 - 1)) : 0;
    med[j] = edges[idx];
  }

  // prop2 for the wave's 4 nodes -> P  (lane = (b:3)(ch8:3))
  const unsigned short* tb = tx1h + lane * 8;
  for (int j = 0; j < 4; ++j) {
    float acc8[8];
#pragma unroll
    for (int q = 0; q < 8; ++q) acc8[q] = 0.0f;
    if (cj[j] > 0)
      gather_group(tb, edges, sj[j], sj[j] + cj[j], lane, med[j], acc8);
    us8 o;
#pragma unroll
    for (int q = 0; q < 8; ++q) o[q] = f2bf(acc8[q]);
    *(us8*)&P[j * 8 + (lane >> 3)][(lane & 7) * 8] = o;
  }

  // MFMA: 2 M-tiles x 4 N-tiles, K=192 in 6 steps of 32
  f4v acc[2][4];
#pragma unroll
  for (int mt = 0; mt < 2; ++mt)
#pragma unroll
    for (int nt = 0; nt < 4; ++nt) acc[mt][nt] = (f4v){0.f, 0.f, 0.f, 0.f};

  int am = lane & 15, aq = (lane >> 4) * 8;
#pragma unroll
  for (int ks = 0; ks < 6; ++ks) {
    s8v a0, a1;
    if (ks < 2) {
      a0 = __builtin_nontemporal_load((const s8v*)&xh[(size_t)(row0 + am) * 64 + ks * 32 + aq]);
      a1 = __builtin_nontemporal_load((const s8v*)&xh[(size_t)(row0 + 16 + am) * 64 + ks * 32 + aq]);
    } else if (ks < 4) {
      // REGULAR loads (not NT): tx1h lines are gather-hot in this kernel
      a0 = *(const s8v*)&tx1h[(size_t)(row0 + am) * 64 + (ks - 2) * 32 + aq];
      a1 = *(const s8v*)&tx1h[(size_t)(row0 + 16 + am) * 64 + (ks - 2) * 32 + aq];
    } else {
      a0 = *(const s8v*)&P[am][(ks - 4) * 32 + aq];
      a1 = *(const s8v*)&P[16 + am][(ks - 4) * 32 + aq];
    }
#pragma unroll
    for (int nt = 0; nt < 4; ++nt) {
      s8v b = *(const s8v*)&pack[(((size_t)(ks * 4 + nt) * 64) + lane) * 8];
      acc[0][nt] = __builtin_amdgcn_mfma_f32_16x16x32_bf16(a0, b, acc[0][nt], 0, 0, 0);
      acc[1][nt] = __builtin_amdgcn_mfma_f32_16x16x32_bf16(a1, b, acc[1][nt], 0, 0, 0);
    }
  }

  // epilogue: + bias, NT store to out (bnc fp32). C/D: row=(lane>>4)*4+r, col=lane&15
  float bv[4];
#pragma unroll
  for (int nt = 0; nt < 4; ++nt) bv[nt] = bias[nt * 16 + (lane & 15)];
#pragma unroll
  for (int mt = 0; mt < 2; ++mt)
#pragma unroll
    for (int r = 0; r < 4; ++r) {
      int rl = mt * 16 + (lane >> 4) * 4 + r;
      int rn = row0 + rl;
      int b = rn & 7, nn = rn >> 3;
      float* orow = &out[((size_t)b * NN + nn) * 64 + (lane & 15)];
#pragma unroll
      for (int nt = 0; nt < 4; ++nt)
        __builtin_nontemporal_store(acc[mt][nt][r] + bv[nt], &orow[nt * 16]);
    }
}

// ---- fallback fp32 kernels (small-ws tiers) --------------------------------
__global__ __launch_bounds__(256) void cheb_prop(
    const float* __restrict__ tin, float* __restrict__ tout,
    const int* __restrict__ rowptr, const int* __restrict__ cnt,
    const int2* __restrict__ edges, int nwaves) {
  int wid = (blockIdx.x << 2) + (threadIdx.x >> 6);
  if (wid >= nwaves) return;
  int lane = threadIdx.x & 63;
  int b = wid / NN;
  int n = wid - b * NN;
  int s = rowptr[n];
  int e = s + cnt[n];
  const float* base = tin + (size_t)b * NN * NC;
  float acc = 0.0f;
  for (int j = s; j < e; ++j) {
    int2 ed = edges[j];
    acc += __int_as_float(ed.y) * base[(size_t)ed.x * NC + lane];
  }
  tout[((size_t)b * NN + n) * NC + lane] = acc;
}

__global__ __launch_bounds__(256) void cheb_gemm2(
    const float* __restrict__ x, const float* __restrict__ tx1,
    const float* ptx1, const float* __restrict__ wc,
    const float* __restrict__ bias, float* out, int nrows) {
  __shared__ float At[128][64];
  __shared__ float Ws[64][64];
  int tid = threadIdx.x;
  int tx = tid & 15;
  int ty = tid >> 4;
  long row0 = (long)blockIdx.x * 128;
  int sk4 = (tid & 15) * 4;
  int srb = tid >> 4;
  const float* sp[3] = {x, tx1, ptx1};
  float4 pa[8], pw[4];
  auto fetch = [&](int ch) {
    const float* s0 = sp[ch];
#pragma unroll
    for (int rr = 0; rr < 8; ++rr) {
      int roff = srb + rr * 16;
      if (row0 + roff < nrows)
        pa[rr] = *(const float4*)&s0[(size_t)(row0 + roff) * NC + sk4];
      else
        pa[rr] = make_float4(0.f, 0.f, 0.f, 0.f);
    }
#pragma unroll
    for (int ww = 0; ww < 4; ++ww) {
      int e4 = tid + 256 * ww;
      pw[ww] = *(const float4*)&wc[ch * 4096 + (e4 >> 4) * 64 + (e4 & 15) * 4];
    }
  };
  auto commit = [&]() {
#pragma unroll
    for (int rr = 0; rr < 8; ++rr)
      *(float4*)&At[srb + rr * 16][sk4] = pa[rr];
#pragma unroll
    for (int ww = 0; ww < 4; ++ww) {
      int e4 = tid + 256 * ww;
      *(float4*)&Ws[e4 >> 4][(e4 & 15) * 4] = pw[ww];
    }
  };
  float4 acc[8];
#pragma unroll
  for (int i = 0; i < 8; ++i) acc[i] = make_float4(0.f, 0.f, 0.f, 0.f);
  fetch(0);
  commit();
  for (int ch = 0; ch < 3; ++ch) {
    __syncthreads();
    if (ch < 2) fetch(ch + 1);
#pragma unroll 4
    for (int k4 = 0; k4 < 16; ++k4) {
      float4 w0 = *(float4*)&Ws[k4 * 4 + 0][tx * 4];
      float4 w1 = *(float4*)&Ws[k4 * 4 + 1][tx * 4];
      float4 w2 = *(float4*)&Ws[k4 * 4 + 2][tx * 4];
      float4 w3 = *(float4*)&Ws[k4 * 4 + 3][tx * 4];
#pragma unroll
      for (int i = 0; i < 8; ++i) {
        float4 a = *(float4*)&At[ty * 8 + i][k4 * 4];
        fma4(acc[i], a.x, w0);
        fma4(acc[i], a.y, w1);
        fma4(acc[i], a.z, w2);
        fma4(acc[i], a.w, w3);
      }
    }
    __syncthreads();
    if (ch < 2) commit();
  }
  float4 bb4 = *(const float4*)&bias[tx * 4];
#pragma unroll
  for (int i = 0; i < 8; ++i) {
    long r = row0 + ty * 8 + i;
    if (r >= nrows) continue;
    float4 o = make_float4(acc[i].x + bb4.x, acc[i].y + bb4.y,
                           acc[i].z + bb4.z, acc[i].w + bb4.w);
    *(float4*)&out[(size_t)r * NC + tx * 4] = o;
  }
}

extern "C" void kernel_launch(void* const* d_in, const int* in_sizes, int n_in,
                              void* d_out, int out_size, void* d_ws, size_t ws_size,
                              hipStream_t stream) {
  (void)in_sizes; (void)n_in; (void)out_size;
  const float* x    = (const float*)d_in[0];
  const float* w    = (const float*)d_in[1];
  const float* bias = (const float*)d_in[2];
  const int*   ei   = (const int*)d_in[3];
  float* out = (float*)d_out;
  char* ws = (char*)d_ws;

  size_t off = 0;
  auto alloc = [&](size_t bytes) -> void* {
    void* p = (void*)(ws + off);
    off = (off + bytes + 255) & ~(size_t)255;
    return p;
  };
  int* cnt      = (int*)alloc((size_t)(NN + 1) * sizeof(int));
  int* total    = cnt + NN;
  int* rowptr   = (int*)alloc((size_t)NN * sizeof(int));
  int* cur      = (int*)alloc((size_t)NN * sizeof(int));
  float* dinv   = (float*)alloc((size_t)NN * sizeof(float));
  int2* edges   = (int2*)alloc((size_t)NE * sizeof(int2));
  float* wcb    = (float*)alloc((size_t)3 * NC * NC * sizeof(float));
  unsigned short* pack = (unsigned short*)alloc((size_t)6 * 4 * 64 * 8 * sizeof(unsigned short));
  size_t small_end = off;

  hipMemsetAsync(cnt, 0, (NN + 1) * sizeof(int), stream);
  cheb_count  <<<(NE + 255) / 256, 256, 0, stream>>>(ei, cnt);
  cheb_offsets<<<(NN + 255) / 256, 256, 0, stream>>>(cnt, dinv, rowptr, cur, total);
  cheb_scatter<<<(NE + 255) / 256, 256, 0, stream>>>(ei, dinv, cur, edges);

  const size_t fieldHB = (size_t)NN * 512 * sizeof(unsigned short);  // 51.2 MB
  const size_t perbB   = (size_t)NN * NC * sizeof(float);            // 12.8 MB

  if (ws_size >= small_end + 2 * fieldHB + 256) {
    // Tier A: bf16 pipeline with fused prop2+MFMA GEMM
    unsigned short* xh   = (unsigned short*)alloc(fieldHB);
    unsigned short* tx1h = (unsigned short*)alloc(fieldHB);
    cheb_wpack  <<<(6 * 4 * 64 * 8 + 255) / 256, 256, 0, stream>>>(w, pack);
    cheb_convert<<<(NN * 128) / 256, 256, 0, stream>>>(x, xh);
    cheb_prop1h <<<NN / 4, 256, 0, stream>>>(xh, tx1h, rowptr, cnt, edges);
    cheb_fused  <<<(NB * NN) / 128, 256, 0, stream>>>(
        xh, tx1h, rowptr, cnt, edges, pack, bias, out);
  } else if (ws_size >= small_end + 2 * perbB + 256) {
    // Tier B: per-batch fp32 fallback
    cheb_wc<<<(NC * NC + 255) / 256, 256, 0, stream>>>(w, wcb);
    float* tx1b  = (float*)alloc(perbB);
    float* ptx1b = (float*)alloc(perbB);
    for (int b = 0; b < NB; ++b) {
      const float* xb = x + (size_t)b * NN * NC;
      float* outb = out + (size_t)b * NN * NC;
      cheb_prop<<<(NN + 3) / 4, 256, 0, stream>>>(xb, tx1b, rowptr, cnt, edges, NN);
      cheb_prop<<<(NN + 3) / 4, 256, 0, stream>>>(tx1b, ptx1b, rowptr, cnt, edges, NN);
      cheb_gemm2<<<(NN + 127) / 128, 256, 0, stream>>>(
          xb, tx1b, ptx1b, wcb, bias, outb, NN);
    }
  } else {
    // Tier C: per-batch fp32, ptx1 via out slice (gemm stages before writes)
    cheb_wc<<<(NC * NC + 255) / 256, 256, 0, stream>>>(w, wcb);
    float* tx1b = (float*)alloc(perbB);
    for (int b = 0; b < NB; ++b) {
      const float* xb = x + (size_t)b * NN * NC;
      float* outb = out + (size_t)b * NN * NC;
      cheb_prop<<<(NN + 3) / 4, 256, 0, stream>>>(xb, tx1b, rowptr, cnt, edges, NN);
      cheb_prop<<<(NN + 3) / 4, 256, 0, stream>>>(tx1b, outb, rowptr, cnt, edges, NN);
      cheb_gemm2<<<(NN + 127) / 128, 256, 0, stream>>>(
          xb, tx1b, outb, wcb, bias, outb, NN);
    }
  }
}